// Round 9
// baseline (467.852 us; speedup 1.0000x reference)
//
#include <hip/hip_runtime.h>

#define SLEN  512
#define BATCH 256
#define NTAGS 128
#define NTHR  1024   // jp=tid>>4 (0..63): cols j1=2jp,j1+1 ; h=tid&15: i in [8h,8h+8)

// DPP helpers. quad_perm 0xB1/0x4E validated bit-exact r5-r7.
// row_shl:N = dst lane l <- src lane l+N within a 16-lane row (canonical GCN
// DPP-reduction direction: row_shr accumulates to lane 63 => shr is l<-l-N,
// shl is l<-l+N). Lanes with no source get 0 via bound_ctrl (never consumed).
__device__ __forceinline__ int dpp_qperm_b1(int x) {   // lane l <- l^1
    return __builtin_amdgcn_update_dpp(0, x, 0xB1, 0xF, 0xF, true);
}
__device__ __forceinline__ int dpp_qperm_4e(int x) {   // lane l <- l^2
    return __builtin_amdgcn_update_dpp(0, x, 0x4E, 0xF, 0xF, true);
}
__device__ __forceinline__ int dpp_row_shl4(int x) {   // lane l <- l+4
    return __builtin_amdgcn_update_dpp(0, x, 0x104, 0xF, 0xF, true);
}
__device__ __forceinline__ int dpp_row_shl8(int x) {   // lane l <- l+8
    return __builtin_amdgcn_update_dpp(0, x, 0x108, 0xF, 0xF, true);
}

// Value+index pair; b must carry the HIGHER index range:
// strict > keeps the first (lower-index) maximum -> np.argmax tie rule.
struct VI { float v; int i; };
__device__ __forceinline__ VI vmax2(VI a, VI b) { return (b.v > a.v) ? b : a; }

// Reduce (v,gi) to lane h==0 of each 16-lane row. Stage partners of every
// consumed lane hold a HIGHER i-base => strict > == first-occurrence.
// Validity chain: lane0.s4 reads lane8.s3 (= max of its quad + lane12.s2quad),
// lane0.s3 reads lane4.s2; all quad-stage values are complete (xor stages).
__device__ __forceinline__ void bfly16(float& v, int& gi) {
    {
        float vo = __int_as_float(dpp_qperm_b1(__float_as_int(v)));
        int   io = dpp_qperm_b1(gi);
        if (vo > v) { v = vo; gi = io; }
    }
    {
        float vo = __int_as_float(dpp_qperm_4e(__float_as_int(v)));
        int   io = dpp_qperm_4e(gi);
        if (vo > v) { v = vo; gi = io; }
    }
    {
        float vo = __int_as_float(dpp_row_shl4(__float_as_int(v)));
        int   io = dpp_row_shl4(gi);
        if (vo > v) { v = vo; gi = io; }
    }
    {
        float vo = __int_as_float(dpp_row_shl8(__float_as_int(v)));
        int   io = dpp_row_shl8(gi);
        if (vo > v) { v = vo; gi = io; }
    }
}

__global__ __launch_bounds__(NTHR, 4) void viterbi_kernel(
    const float* __restrict__ em,      // [S,B,T]
    const int*   __restrict__ mask,    // [S,B]
    const float* __restrict__ start_t, // [T]
    const float* __restrict__ end_t,   // [T]
    const float* __restrict__ trans,   // [T,T]
    float* __restrict__ out)           // [B*S] tags (as float), then [B] scores
{
    const int b    = blockIdx.x;
    const int tid  = threadIdx.x;
    const int jp   = tid >> 4;         // 0..63
    const int j1   = jp << 1;          // even column
    const int h    = tid & 15;         // 0..15
    const int base = h << 3;           // h*8
    const bool writer = (h == 0);
    // sc chunk h (8 floats) lives at float offset h*12 (48B stride: 16B-aligned;
    // chunks h and h+8 share banks -> 2-way conflict = free per m136)
    const int jslot = (j1 >> 3) * 12 + (j1 & 7);

    __shared__ __align__(16) float scbuf[2][16 * 12];
    __shared__ float fin[NTAGS];
    __shared__ int   maskv[SLEN];
    __shared__ unsigned char hist[SLEN - 1][NTAGS];   // 65408 B
    __shared__ unsigned char exitc[8][NTAGS];
    __shared__ unsigned char st_tags[8];
    __shared__ unsigned char tagseq[SLEN];
    __shared__ float bestval_s;
    __shared__ int   bestj_s;

    // Transition registers: taK = trans[base+K][j1], tbK = trans[base+K][j1+1]
    const float* trp = trans + (size_t)base * NTAGS + j1;
    const float2 w0 = *(const float2*)(trp + 0 * NTAGS);
    const float2 w1 = *(const float2*)(trp + 1 * NTAGS);
    const float2 w2 = *(const float2*)(trp + 2 * NTAGS);
    const float2 w3 = *(const float2*)(trp + 3 * NTAGS);
    const float2 w4 = *(const float2*)(trp + 4 * NTAGS);
    const float2 w5 = *(const float2*)(trp + 5 * NTAGS);
    const float2 w6 = *(const float2*)(trp + 6 * NTAGS);
    const float2 w7 = *(const float2*)(trp + 7 * NTAGS);
    const float ta0 = w0.x, tb0 = w0.y, ta1 = w1.x, tb1 = w1.y;
    const float ta2 = w2.x, tb2 = w2.y, ta3 = w3.x, tb3 = w3.y;
    const float ta4 = w4.x, tb4 = w4.y, ta5 = w5.x, tb5 = w5.y;
    const float ta6 = w6.x, tb6 = w6.y, ta7 = w7.x, tb7 = w7.y;

    if (tid < SLEN)
        maskv[tid] = mask[tid * BATCH + b];

    float scjA = 0.f, scjB = 0.f;
    if (writer) {
        scjA = start_t[j1]     + em[(size_t)b * NTAGS + j1];      // exact ref order
        scjB = start_t[j1 + 1] + em[(size_t)b * NTAGS + j1 + 1];
        scbuf[0][jslot]     = scjA;
        scbuf[0][jslot + 1] = scjB;
    }
    __syncthreads();

    const float2* emp2 = (const float2*)(em + (size_t)BATCH * NTAGS
                                            + (size_t)b * NTAGS + j1); // t=1
    float2 em_next = *emp2;

    int p = 0;
    for (int t = 1; t < SLEN; ++t) {
        const float emA = em_next.x, emB = em_next.y;
        if (t + 1 < SLEN) { emp2 += (BATCH * NTAGS) / 2; em_next = *emp2; }

        // This thread's 8 sc values: 2 broadcast b128 reads
        const float4* sq = (const float4*)&scbuf[p][h * 12];
        const float4 q0 = sq[0], q1 = sq[1];

        // Column A (j1): c_k = fl(fl(sc+tr)+em), exact ref associativity;
        // adjacent-pair tree keeps first-occurrence max.
        const float ac0 = (q0.x + ta0) + emA, ac1 = (q0.y + ta1) + emA;
        const float ac2 = (q0.z + ta2) + emA, ac3 = (q0.w + ta3) + emA;
        const float ac4 = (q1.x + ta4) + emA, ac5 = (q1.y + ta5) + emA;
        const float ac6 = (q1.z + ta6) + emA, ac7 = (q1.w + ta7) + emA;
        const VI am0 = vmax2(VI{ac0, 0}, VI{ac1, 1});
        const VI am1 = vmax2(VI{ac2, 2}, VI{ac3, 3});
        const VI am2 = vmax2(VI{ac4, 4}, VI{ac5, 5});
        const VI am3 = vmax2(VI{ac6, 6}, VI{ac7, 7});
        const VI an0 = vmax2(am0, am1), an1 = vmax2(am2, am3);
        const VI ar  = vmax2(an0, an1);

        // Column B (j1+1)
        const float bc0 = (q0.x + tb0) + emB, bc1 = (q0.y + tb1) + emB;
        const float bc2 = (q0.z + tb2) + emB, bc3 = (q0.w + tb3) + emB;
        const float bc4 = (q1.x + tb4) + emB, bc5 = (q1.y + tb5) + emB;
        const float bc6 = (q1.z + tb6) + emB, bc7 = (q1.w + tb7) + emB;
        const VI bm0 = vmax2(VI{bc0, 0}, VI{bc1, 1});
        const VI bm1 = vmax2(VI{bc2, 2}, VI{bc3, 3});
        const VI bm2 = vmax2(VI{bc4, 4}, VI{bc5, 5});
        const VI bm3 = vmax2(VI{bc6, 6}, VI{bc7, 7});
        const VI bn0 = vmax2(bm0, bm1), bn1 = vmax2(bm2, bm3);
        const VI br  = vmax2(bn0, bn1);

        float vA = ar.v;  int giA = base + ar.i;
        float vB = br.v;  int giB = base + br.i;
        bfly16(vA, giA);
        bfly16(vB, giB);

        if (writer) {
            hist[t - 1][j1]     = (unsigned char)giA;   // recorded unconditionally
            hist[t - 1][j1 + 1] = (unsigned char)giB;
            const int mm = maskv[t];
            scjA = mm ? vA : scjA;                      // where(mask, next, old)
            scjB = mm ? vB : scjB;
            scbuf[p ^ 1][jslot]     = scjA;
            scbuf[p ^ 1][jslot + 1] = scjB;
        }
        __syncthreads();
        p ^= 1;
    }

    // final = sc + end_transitions, straight from writer registers
    if (writer) {
        fin[j1]     = scjA + end_t[j1];
        fin[j1 + 1] = scjB + end_t[j1 + 1];
    }
    __syncthreads();

    // first-occurrence argmax over 128 tags (wave 0)
    if (tid < 64) {
        float v  = fin[tid]; int bj = tid;
        float v1 = fin[tid + 64];
        if (v1 > v) { v = v1; bj = tid + 64; }
#pragma unroll
        for (int off = 32; off > 0; off >>= 1) {
            float ov = __shfl_xor(v, off, 64);
            int   oj = __shfl_xor(bj, off, 64);
            if (ov > v || (ov == v && oj < bj)) { v = ov; bj = oj; }
        }
        if (tid == 0) { bestval_s = v; bestj_s = bj; }
    }
    __syncthreads();

    // ---- Chunked parallel backtrace: 8 chunks x 128 tags = 1 chain/thread
    // (verbatim from round 7's passing kernel) ----
    {
        const int k = tid & 127;
        const int c = tid >> 7;        // 0..7
        int tag = k;
        for (int u = 63; u >= 0; --u) {
            const int s = c * 64 + u;
            if (s <= SLEN - 2) {
                int pv = hist[s][tag];
                tag = maskv[s + 1] ? pv : tag;
            }
        }
        exitc[c][k] = (unsigned char)tag;
    }
    __syncthreads();

    if (tid == 0) {
        int tag = bestj_s;
        for (int c = 7; c >= 0; --c) {
            st_tags[c] = (unsigned char)tag;
            tag = exitc[c][tag];
        }
        out[BATCH * SLEN + b] = bestval_s;        // best_path_score
    }
    __syncthreads();

    if (tid < 8) {
        const int c = tid;
        int tag = st_tags[c];
        if (c == 7) tagseq[SLEN - 1] = (unsigned char)tag;
        const int shi = (c == 7) ? (SLEN - 2) : (c * 64 + 63);
        for (int s = shi; s >= c * 64; --s) {
            int pv = hist[s][tag];
            tag = maskv[s + 1] ? pv : tag;
            tagseq[s] = (unsigned char)tag;
        }
    }
    __syncthreads();

    // Coalesced tag writeout as float: out0 is tags.T -> [B, S] row-major
    if (tid < SLEN)
        out[b * SLEN + tid] = (float)tagseq[tid];
}

extern "C" void kernel_launch(void* const* d_in, const int* in_sizes, int n_in,
                              void* d_out, int out_size, void* d_ws, size_t ws_size,
                              hipStream_t stream) {
    const float* em      = (const float*)d_in[0];
    const int*   mask    = (const int*)d_in[1];
    const float* start_t = (const float*)d_in[2];
    const float* end_t   = (const float*)d_in[3];
    const float* trans   = (const float*)d_in[4];
    float* out = (float*)d_out;

    viterbi_kernel<<<dim3(BATCH), dim3(NTHR), 0, stream>>>(
        em, mask, start_t, end_t, trans, out);
}

// Round 10
// 429.676 us; speedup vs baseline: 1.0888x; 1.0888x over previous
//
#include <hip/hip_runtime.h>

#define SLEN  512
#define BATCH 256
#define NTAGS 128
#define NTHR  1024   // j = tid>>3 (0..127), h = tid&7 -> 16 waves, 4/SIMD

// quad_perm DPP within a quad (pure VALU) - validated bit-exact r5-r9
__device__ __forceinline__ int dpp_qperm_b1(int x) {  // lane <- lane^1
    return __builtin_amdgcn_update_dpp(0, x, 0xB1, 0xF, 0xF, true);
}
__device__ __forceinline__ int dpp_qperm_4e(int x) {  // lane <- lane^2
    return __builtin_amdgcn_update_dpp(0, x, 0x4E, 0xF, 0xF, true);
}
__device__ __forceinline__ int swz_xor4(int x) {      // lane <- lane^4 (validated r6)
    return __builtin_amdgcn_ds_swizzle(x, 0x101F);
}

// Value+index pair; b must carry the HIGHER index range:
// strict > keeps the first (lower-index) maximum -> np.argmax tie rule.
struct VI { float v; int i; };
__device__ __forceinline__ VI vmax2(VI a, VI b) { return (b.v > a.v) ? b : a; }

__global__ __launch_bounds__(NTHR, 4) void viterbi_kernel(
    const float* __restrict__ em,      // [S,B,T]
    const int*   __restrict__ mask,    // [S,B]
    const float* __restrict__ start_t, // [T]
    const float* __restrict__ end_t,   // [T]
    const float* __restrict__ trans,   // [T,T]
    float* __restrict__ out)           // [B*S] tags (as float), then [B] scores
{
    const int b    = blockIdx.x;
    const int tid  = threadIdx.x;
    const int j    = tid >> 3;         // 0..127
    const int h    = tid & 7;          // 0..7
    const int base = h << 4;           // h*16
    const bool writer = (h == 0);
    const int jslot = j + (j >> 4) * 4;   // chunk j>>4 at float offset (j>>4)*20

    // sc double-buffer; chunk h at float offset h*20 -> the 8 distinct b128
    // addresses of a wave-read cover all 32 banks (conflict-free)
    __shared__ __align__(16) float scbuf[2][8 * 20];
    __shared__ float fin[NTAGS];
    __shared__ int   maskv[SLEN];
    __shared__ unsigned char hist[SLEN - 1][NTAGS];   // 65408 B
    __shared__ unsigned char exitc[8][NTAGS];
    __shared__ unsigned char st_tags[8];
    __shared__ unsigned char tagseq[SLEN];
    __shared__ float bestval_s;
    __shared__ int   bestj_s;

    // ---- 16 NAMED transition-column registers: trans[base+k][j] ----
    const float* trp = trans + (size_t)base * NTAGS + j;
    float t00 = trp[ 0*NTAGS], t01 = trp[ 1*NTAGS], t02 = trp[ 2*NTAGS], t03 = trp[ 3*NTAGS];
    float t04 = trp[ 4*NTAGS], t05 = trp[ 5*NTAGS], t06 = trp[ 6*NTAGS], t07 = trp[ 7*NTAGS];
    float t08 = trp[ 8*NTAGS], t09 = trp[ 9*NTAGS], t10 = trp[10*NTAGS], t11 = trp[11*NTAGS];
    float t12 = trp[12*NTAGS], t13 = trp[13*NTAGS], t14 = trp[14*NTAGS], t15 = trp[15*NTAGS];

    if (tid < SLEN)
        maskv[tid] = mask[tid * BATCH + b];

    float scj = 0.f;
    if (writer) {
        scj = start_t[j] + em[(size_t)b * NTAGS + j];   // exact ref associativity
        scbuf[0][jslot] = scj;
    }
    __syncthreads();

    const float* emp = em + (size_t)BATCH * NTAGS + (size_t)b * NTAGS + j; // t=1
    float em_next = *emp;

    int p = 0;
    for (int t = 1; t < SLEN; ++t) {
        // LOOP-CARRIED opaque def: each iteration's trans values flow through
        // this asm (prev iteration -> this one). The compiler can no longer
        // rematerialize the global loads per-iteration (r6/r7/r9: VGPR=28
        // proved it did; dur tracked the inflated emitted-inst count).
        asm volatile("" : "+v"(t00), "+v"(t01), "+v"(t02), "+v"(t03),
                          "+v"(t04), "+v"(t05), "+v"(t06), "+v"(t07),
                          "+v"(t08), "+v"(t09), "+v"(t10), "+v"(t11),
                          "+v"(t12), "+v"(t13), "+v"(t14), "+v"(t15));

        const float em_cur = em_next;
        if (t + 1 < SLEN) { emp += BATCH * NTAGS; em_next = *emp; }

        // 4 named float4 broadcast reads of this thread's 16-float sc chunk
        const float4* sq = (const float4*)&scbuf[p][h * 20];
        const float4 q0 = sq[0], q1 = sq[1], q2 = sq[2], q3 = sq[3];

        // 16 candidates: c_k = fl(fl(sc[base+k] + trans[base+k][j]) + em) — exact ref order
        const float c00 = (q0.x + t00) + em_cur, c01 = (q0.y + t01) + em_cur;
        const float c02 = (q0.z + t02) + em_cur, c03 = (q0.w + t03) + em_cur;
        const float c04 = (q1.x + t04) + em_cur, c05 = (q1.y + t05) + em_cur;
        const float c06 = (q1.z + t06) + em_cur, c07 = (q1.w + t07) + em_cur;
        const float c08 = (q2.x + t08) + em_cur, c09 = (q2.y + t09) + em_cur;
        const float c10 = (q2.z + t10) + em_cur, c11 = (q2.w + t11) + em_cur;
        const float c12 = (q3.x + t12) + em_cur, c13 = (q3.y + t13) + em_cur;
        const float c14 = (q3.z + t14) + em_cur, c15 = (q3.w + t15) + em_cur;

        // Adjacent-pair tree, all named: strict > at every level == first-occurrence
        const VI m0 = vmax2(VI{c00, 0}, VI{c01, 1}),  m1 = vmax2(VI{c02, 2}, VI{c03, 3});
        const VI m2 = vmax2(VI{c04, 4}, VI{c05, 5}),  m3 = vmax2(VI{c06, 6}, VI{c07, 7});
        const VI m4 = vmax2(VI{c08, 8}, VI{c09, 9}),  m5 = vmax2(VI{c10,10}, VI{c11,11});
        const VI m6 = vmax2(VI{c12,12}, VI{c13,13}),  m7 = vmax2(VI{c14,14}, VI{c15,15});
        const VI n0 = vmax2(m0, m1), n1 = vmax2(m2, m3);
        const VI n2 = vmax2(m4, m5), n3 = vmax2(m6, m7);
        const VI o0 = vmax2(n0, n1), o1 = vmax2(n2, n3);
        const VI r  = vmax2(o0, o1);

        // 3-stage butterfly over h (validated bit-exact r6/r7): partners hold
        // HIGHER i-base from the h==0 lane's view -> strict > keeps first max.
        float v  = r.v;
        int   gi = base + r.i;
        {
            float vo = __int_as_float(dpp_qperm_b1(__float_as_int(v)));
            int   io = dpp_qperm_b1(gi);
            if (vo > v) { v = vo; gi = io; }
        }
        {
            float vo = __int_as_float(dpp_qperm_4e(__float_as_int(v)));
            int   io = dpp_qperm_4e(gi);
            if (vo > v) { v = vo; gi = io; }
        }
        {
            float vo = __int_as_float(swz_xor4(__float_as_int(v)));
            int   io = swz_xor4(gi);
            if (vo > v) { v = vo; gi = io; }
        }

        if (writer) {
            hist[t - 1][j] = (unsigned char)gi;   // recorded unconditionally (ref does too)
            scj = maskv[t] ? v : scj;             // where(mask, next, old), register-carried
            scbuf[p ^ 1][jslot] = scj;
        }
        __syncthreads();                           // ONE barrier per step
        p ^= 1;
    }

    // final = sc + end_transitions, straight from writer registers
    if (writer) fin[j] = scj + end_t[j];
    __syncthreads();

    // first-occurrence argmax over 128 tags (wave 0)
    if (tid < 64) {
        float v  = fin[tid]; int bj = tid;
        float v1 = fin[tid + 64];
        if (v1 > v) { v = v1; bj = tid + 64; }
#pragma unroll
        for (int off = 32; off > 0; off >>= 1) {
            float ov = __shfl_xor(v, off, 64);
            int   oj = __shfl_xor(bj, off, 64);
            if (ov > v || (ov == v && oj < bj)) { v = ov; bj = oj; }
        }
        if (tid == 0) { bestval_s = v; bestj_s = bj; }
    }
    __syncthreads();

    // ---- Chunked parallel backtrace: 8 chunks x 128 tags = 1 chain/thread ----
    {
        const int k = tid & 127;
        const int c = tid >> 7;        // 0..7
        int tag = k;
        for (int u = 63; u >= 0; --u) {
            const int s = c * 64 + u;
            if (s <= SLEN - 2) {
                int pv = hist[s][tag];
                tag = maskv[s + 1] ? pv : tag;
            }
        }
        exitc[c][k] = (unsigned char)tag;
    }
    __syncthreads();

    if (tid == 0) {
        int tag = bestj_s;
        for (int c = 7; c >= 0; --c) {
            st_tags[c] = (unsigned char)tag;
            tag = exitc[c][tag];
        }
        out[BATCH * SLEN + b] = bestval_s;        // best_path_score
    }
    __syncthreads();

    if (tid < 8) {
        const int c = tid;
        int tag = st_tags[c];
        if (c == 7) tagseq[SLEN - 1] = (unsigned char)tag;
        const int shi = (c == 7) ? (SLEN - 2) : (c * 64 + 63);
        for (int s = shi; s >= c * 64; --s) {
            int pv = hist[s][tag];
            tag = maskv[s + 1] ? pv : tag;
            tagseq[s] = (unsigned char)tag;
        }
    }
    __syncthreads();

    // Coalesced tag writeout as float: out0 is tags.T -> [B, S] row-major
    if (tid < SLEN)
        out[b * SLEN + tid] = (float)tagseq[tid];
}

extern "C" void kernel_launch(void* const* d_in, const int* in_sizes, int n_in,
                              void* d_out, int out_size, void* d_ws, size_t ws_size,
                              hipStream_t stream) {
    const float* em      = (const float*)d_in[0];
    const int*   mask    = (const int*)d_in[1];
    const float* start_t = (const float*)d_in[2];
    const float* end_t   = (const float*)d_in[3];
    const float* trans   = (const float*)d_in[4];
    float* out = (float*)d_out;

    viterbi_kernel<<<dim3(BATCH), dim3(NTHR), 0, stream>>>(
        em, mask, start_t, end_t, trans, out);
}

// Round 11
// 411.468 us; speedup vs baseline: 1.1370x; 1.0443x over previous
//
#include <hip/hip_runtime.h>

#define SLEN  512
#define BATCH 256
#define NTAGS 128
#define NTHR  512   // jp=tid>>3 (0..63): cols j1=2jp, j1+1 ; h=tid&7: i in [16h,16h+16)

// Combine stages, all validated bit-exact on this problem (r5-r7, r10):
__device__ __forceinline__ int dpp_qperm_b1(int x) {  // lane <- lane^1
    return __builtin_amdgcn_update_dpp(0, x, 0xB1, 0xF, 0xF, true);
}
__device__ __forceinline__ int dpp_qperm_4e(int x) {  // lane <- lane^2
    return __builtin_amdgcn_update_dpp(0, x, 0x4E, 0xF, 0xF, true);
}
__device__ __forceinline__ int swz_xor4(int x) {      // lane <- lane^4
    return __builtin_amdgcn_ds_swizzle(x, 0x101F);
}

// Value+index pair; b must carry the HIGHER index range:
// strict > keeps the first (lower-index) maximum -> np.argmax tie rule.
struct VI { float v; int i; };
__device__ __forceinline__ VI vmax2(VI a, VI b) { return (b.v > a.v) ? b : a; }

// Reduce over the 8 h-groups; only h==0 lane's result is consumed. Partners
// of consumed lanes always hold a HIGHER i-base -> strict > keeps first max.
__device__ __forceinline__ void bfly8(float& v, int& gi) {
    {
        float vo = __int_as_float(dpp_qperm_b1(__float_as_int(v)));
        int   io = dpp_qperm_b1(gi);
        if (vo > v) { v = vo; gi = io; }
    }
    {
        float vo = __int_as_float(dpp_qperm_4e(__float_as_int(v)));
        int   io = dpp_qperm_4e(gi);
        if (vo > v) { v = vo; gi = io; }
    }
    {
        float vo = __int_as_float(swz_xor4(__float_as_int(v)));
        int   io = swz_xor4(gi);
        if (vo > v) { v = vo; gi = io; }
    }
}

__global__ __launch_bounds__(NTHR, 2) void viterbi_kernel(
    const float* __restrict__ em,      // [S,B,T]
    const int*   __restrict__ mask,    // [S,B]
    const float* __restrict__ start_t, // [T]
    const float* __restrict__ end_t,   // [T]
    const float* __restrict__ trans,   // [T,T]
    float* __restrict__ out)           // [B*S] tags (as float), then [B] scores
{
    const int b    = blockIdx.x;
    const int tid  = threadIdx.x;
    const int jp   = tid >> 3;         // 0..63
    const int j1   = jp << 1;          // even column
    const int h    = tid & 7;          // 0..7
    const int base = h << 4;           // h*16
    const bool writer = (h == 0);
    const int jslot = j1 + ((j1 >> 4) << 2);   // chunk c=j1>>4 at float offset c*20

    // sc double-buffer; chunk h (16 floats) at float offset h*20 -> the 8
    // distinct b128 addresses per wave-read cover all 32 banks (conflict-free)
    __shared__ __align__(16) float scbuf[2][8 * 20];
    __shared__ float fin[NTAGS];
    __shared__ int   maskv[SLEN];
    __shared__ unsigned char hist[SLEN - 1][NTAGS];   // 65408 B
    __shared__ unsigned char exitc[8][NTAGS];
    __shared__ unsigned char st_tags[8];
    __shared__ unsigned char tagseq[SLEN];
    __shared__ float bestval_s;
    __shared__ int   bestj_s;

    // Transition registers for BOTH columns: taK = trans[base+K][j1], tbK = [j1+1]
    const float* trp = trans + (size_t)base * NTAGS + j1;
    const float2 w00 = *(const float2*)(trp +  0*NTAGS), w01 = *(const float2*)(trp +  1*NTAGS);
    const float2 w02 = *(const float2*)(trp +  2*NTAGS), w03 = *(const float2*)(trp +  3*NTAGS);
    const float2 w04 = *(const float2*)(trp +  4*NTAGS), w05 = *(const float2*)(trp +  5*NTAGS);
    const float2 w06 = *(const float2*)(trp +  6*NTAGS), w07 = *(const float2*)(trp +  7*NTAGS);
    const float2 w08 = *(const float2*)(trp +  8*NTAGS), w09 = *(const float2*)(trp +  9*NTAGS);
    const float2 w10 = *(const float2*)(trp + 10*NTAGS), w11 = *(const float2*)(trp + 11*NTAGS);
    const float2 w12 = *(const float2*)(trp + 12*NTAGS), w13 = *(const float2*)(trp + 13*NTAGS);
    const float2 w14 = *(const float2*)(trp + 14*NTAGS), w15 = *(const float2*)(trp + 15*NTAGS);
    const float ta00 = w00.x, tb00 = w00.y, ta01 = w01.x, tb01 = w01.y;
    const float ta02 = w02.x, tb02 = w02.y, ta03 = w03.x, tb03 = w03.y;
    const float ta04 = w04.x, tb04 = w04.y, ta05 = w05.x, tb05 = w05.y;
    const float ta06 = w06.x, tb06 = w06.y, ta07 = w07.x, tb07 = w07.y;
    const float ta08 = w08.x, tb08 = w08.y, ta09 = w09.x, tb09 = w09.y;
    const float ta10 = w10.x, tb10 = w10.y, ta11 = w11.x, tb11 = w11.y;
    const float ta12 = w12.x, tb12 = w12.y, ta13 = w13.x, tb13 = w13.y;
    const float ta14 = w14.x, tb14 = w14.y, ta15 = w15.x, tb15 = w15.y;

    if (tid < SLEN)                    // NTHR==512==SLEN: all threads
        maskv[tid] = mask[tid * BATCH + b];

    float scjA = 0.f, scjB = 0.f;
    if (writer) {
        scjA = start_t[j1]     + em[(size_t)b * NTAGS + j1];      // exact ref order
        scjB = start_t[j1 + 1] + em[(size_t)b * NTAGS + j1 + 1];
        scbuf[0][jslot]     = scjA;
        scbuf[0][jslot + 1] = scjB;
    }
    __syncthreads();

    const float2* emp2 = (const float2*)(em + (size_t)BATCH * NTAGS
                                            + (size_t)b * NTAGS + j1); // t=1
    float2 em_next = *emp2;

    int p = 0;
    for (int t = 1; t < SLEN; ++t) {
        const float emA = em_next.x, emB = em_next.y;
        if (t + 1 < SLEN) { emp2 += (BATCH * NTAGS) / 2; em_next = *emp2; }

        // This thread's 16 sc values: 4 broadcast b128 reads (shared by both cols)
        const float4* sq = (const float4*)&scbuf[p][h * 20];
        const float4 q0 = sq[0], q1 = sq[1], q2 = sq[2], q3 = sq[3];

        // Column A (j1): c_k = fl(fl(sc+tr)+em) — exact ref associativity;
        // adjacent-pair tree keeps first-occurrence max.
        const float a00 = (q0.x + ta00) + emA, a01 = (q0.y + ta01) + emA;
        const float a02 = (q0.z + ta02) + emA, a03 = (q0.w + ta03) + emA;
        const float a04 = (q1.x + ta04) + emA, a05 = (q1.y + ta05) + emA;
        const float a06 = (q1.z + ta06) + emA, a07 = (q1.w + ta07) + emA;
        const float a08 = (q2.x + ta08) + emA, a09 = (q2.y + ta09) + emA;
        const float a10 = (q2.z + ta10) + emA, a11 = (q2.w + ta11) + emA;
        const float a12 = (q3.x + ta12) + emA, a13 = (q3.y + ta13) + emA;
        const float a14 = (q3.z + ta14) + emA, a15 = (q3.w + ta15) + emA;
        const VI Am0 = vmax2(VI{a00, 0}, VI{a01, 1}),  Am1 = vmax2(VI{a02, 2}, VI{a03, 3});
        const VI Am2 = vmax2(VI{a04, 4}, VI{a05, 5}),  Am3 = vmax2(VI{a06, 6}, VI{a07, 7});
        const VI Am4 = vmax2(VI{a08, 8}, VI{a09, 9}),  Am5 = vmax2(VI{a10,10}, VI{a11,11});
        const VI Am6 = vmax2(VI{a12,12}, VI{a13,13}),  Am7 = vmax2(VI{a14,14}, VI{a15,15});
        const VI An0 = vmax2(Am0, Am1), An1 = vmax2(Am2, Am3);
        const VI An2 = vmax2(Am4, Am5), An3 = vmax2(Am6, Am7);
        const VI Ao0 = vmax2(An0, An1), Ao1 = vmax2(An2, An3);
        const VI Ar  = vmax2(Ao0, Ao1);

        // Column B (j1+1)
        const float b00 = (q0.x + tb00) + emB, b01 = (q0.y + tb01) + emB;
        const float b02 = (q0.z + tb02) + emB, b03 = (q0.w + tb03) + emB;
        const float b04 = (q1.x + tb04) + emB, b05 = (q1.y + tb05) + emB;
        const float b06 = (q1.z + tb06) + emB, b07 = (q1.w + tb07) + emB;
        const float b08 = (q2.x + tb08) + emB, b09 = (q2.y + tb09) + emB;
        const float b10 = (q2.z + tb10) + emB, b11 = (q2.w + tb11) + emB;
        const float b12 = (q3.x + tb12) + emB, b13 = (q3.y + tb13) + emB;
        const float b14 = (q3.z + tb14) + emB, b15 = (q3.w + tb15) + emB;
        const VI Bm0 = vmax2(VI{b00, 0}, VI{b01, 1}),  Bm1 = vmax2(VI{b02, 2}, VI{b03, 3});
        const VI Bm2 = vmax2(VI{b04, 4}, VI{b05, 5}),  Bm3 = vmax2(VI{b06, 6}, VI{b07, 7});
        const VI Bm4 = vmax2(VI{b08, 8}, VI{b09, 9}),  Bm5 = vmax2(VI{b10,10}, VI{b11,11});
        const VI Bm6 = vmax2(VI{b12,12}, VI{b13,13}),  Bm7 = vmax2(VI{b14,14}, VI{b15,15});
        const VI Bn0 = vmax2(Bm0, Bm1), Bn1 = vmax2(Bm2, Bm3);
        const VI Bn2 = vmax2(Bm4, Bm5), Bn3 = vmax2(Bm6, Bm7);
        const VI Bo0 = vmax2(Bn0, Bn1), Bo1 = vmax2(Bn2, Bn3);
        const VI Br  = vmax2(Bo0, Bo1);

        float vA = Ar.v;  int giA = base + Ar.i;
        float vB = Br.v;  int giB = base + Br.i;
        bfly8(vA, giA);
        bfly8(vB, giB);

        if (writer) {
            hist[t - 1][j1]     = (unsigned char)giA;   // recorded unconditionally
            hist[t - 1][j1 + 1] = (unsigned char)giB;
            const int mm = maskv[t];
            scjA = mm ? vA : scjA;                      // where(mask, next, old)
            scjB = mm ? vB : scjB;
            scbuf[p ^ 1][jslot]     = scjA;
            scbuf[p ^ 1][jslot + 1] = scjB;
        }
        // LDS-visibility barrier WITHOUT vmcnt drain (validated r7):
        asm volatile("s_waitcnt lgkmcnt(0)\n\ts_barrier" ::: "memory");
        p ^= 1;
    }

    // final = sc + end_transitions, straight from writer registers
    if (writer) {
        fin[j1]     = scjA + end_t[j1];
        fin[j1 + 1] = scjB + end_t[j1 + 1];
    }
    __syncthreads();

    // first-occurrence argmax over 128 tags (wave 0)
    if (tid < 64) {
        float v  = fin[tid]; int bj = tid;
        float v1 = fin[tid + 64];
        if (v1 > v) { v = v1; bj = tid + 64; }
#pragma unroll
        for (int off = 32; off > 0; off >>= 1) {
            float ov = __shfl_xor(v, off, 64);
            int   oj = __shfl_xor(bj, off, 64);
            if (ov > v || (ov == v && oj < bj)) { v = ov; bj = oj; }
        }
        if (tid == 0) { bestval_s = v; bestj_s = bj; }
    }
    __syncthreads();

    // ---- Chunked parallel backtrace, 2 chains/thread (validated r3-r5) ----
    {
        const int k  = tid & 127;
        const int c0 = tid >> 7;       // 0..3
        const int c1 = c0 + 4;         // 4..7
        int tagA = k, tagB = k;
        for (int u = 63; u >= 0; --u) {
            const int sA = c0 * 64 + u;
            const int sB = c1 * 64 + u;
            if (sB <= SLEN - 2) {
                int pv = hist[sB][tagB];
                tagB = maskv[sB + 1] ? pv : tagB;
            }
            int pv = hist[sA][tagA];
            tagA = maskv[sA + 1] ? pv : tagA;
        }
        exitc[c0][k] = (unsigned char)tagA;
        exitc[c1][k] = (unsigned char)tagB;
    }
    __syncthreads();

    if (tid == 0) {
        int tag = bestj_s;
        for (int c = 7; c >= 0; --c) {
            st_tags[c] = (unsigned char)tag;
            tag = exitc[c][tag];
        }
        out[BATCH * SLEN + b] = bestval_s;        // best_path_score
    }
    __syncthreads();

    if (tid < 8) {
        const int c = tid;
        int tag = st_tags[c];
        if (c == 7) tagseq[SLEN - 1] = (unsigned char)tag;
        const int shi = (c == 7) ? (SLEN - 2) : (c * 64 + 63);
        for (int s = shi; s >= c * 64; --s) {
            int pv = hist[s][tag];
            tag = maskv[s + 1] ? pv : tag;
            tagseq[s] = (unsigned char)tag;
        }
    }
    __syncthreads();

    // Coalesced tag writeout as float: out0 is tags.T -> [B, S] row-major
    out[b * SLEN + tid] = (float)tagseq[tid];
}

extern "C" void kernel_launch(void* const* d_in, const int* in_sizes, int n_in,
                              void* d_out, int out_size, void* d_ws, size_t ws_size,
                              hipStream_t stream) {
    const float* em      = (const float*)d_in[0];
    const int*   mask    = (const int*)d_in[1];
    const float* start_t = (const float*)d_in[2];
    const float* end_t   = (const float*)d_in[3];
    const float* trans   = (const float*)d_in[4];
    float* out = (float*)d_out;

    viterbi_kernel<<<dim3(BATCH), dim3(NTHR), 0, stream>>>(
        em, mask, start_t, end_t, trans, out);
}